// Round 1
// baseline (353.996 us; speedup 1.0000x reference)
//
#include <hip/hip_runtime.h>
#include <math.h>

// CTC batch cost: B=256, T=256, C=1024, L=32 -> S=65 extended states.
// One block per batch element. Waves 1..3 gather log-probs of the 65
// extended-label classes into double-buffered LDS chunks of 64 timesteps;
// wave 0 runs the alpha recursion with states in registers (lane i holds
// states 2i and 2i+1, neighbors via shfl_up).

#define Bt 256
#define Tt 256
#define Ct 1024
#define Lt 32
#define St 65          // 2*L+1 extended states
#define SP 66          // padded LDS row stride (floats)
#define CH 64          // timesteps per chunk
#define NCH (Tt / CH)
#define NEGV (-1e30f)
#define EPSV (1e-7f)

__device__ __forceinline__ float lae2(float a, float b) {
    float m = fmaxf(a, b);
    return m + __logf(__expf(a - m) + __expf(b - m));
}

__device__ __forceinline__ float lae3(float a, float b, float c) {
    float m = fmaxf(fmaxf(a, b), c);
    return m + __logf(__expf(a - m) + __expf(b - m) + __expf(c - m));
}

__global__ __launch_bounds__(256) void ctc_kernel(const int* __restrict__ y_true,
                                                  const float* __restrict__ y_pred,
                                                  float* __restrict__ out) {
    __shared__ float lp[2][CH][SP];
    __shared__ int ext_cls[St];
    __shared__ unsigned char skip_ok[St];
    __shared__ int s_ll;
    __shared__ float alpha_f[SP];

    const int b = blockIdx.x;
    const int tid = threadIdx.x;
    const int lane = tid & 63;
    const int blank = Ct - 1;
    const float* yp = y_pred + (size_t)b * Tt * Ct;
    const int* lab = y_true + b * Lt;

    // ---- phase A: extended label sequence + skip flags + label length ----
    if (tid < St) {
        int cls = blank;
        if (tid & 1) cls = lab[(tid - 1) >> 1];
        ext_cls[tid] = cls;
    }
    __syncthreads();
    if (tid < St) {
        int ok = 0;
        if (tid & 1) {
            int prev2 = (tid >= 2) ? ext_cls[tid - 2] : -1;
            ok = (ext_cls[tid] != blank && ext_cls[tid] != prev2) ? 1 : 0;
        }
        skip_ok[tid] = (unsigned char)ok;
    }
    if (tid == 0) {
        int ll = 0;
        for (int j = 0; j < Lt; ++j) ll += (lab[j] != 0) ? 1 : 0;
        s_ll = ll;
    }
    __syncthreads();

    // ---- prologue: gather chunk 0 with all threads ----
    for (int idx = tid; idx < CH * St; idx += 256) {
        int tt = idx / St;
        int s = idx - tt * St;
        lp[0][tt][s] = __logf(yp[tt * Ct + ext_cls[s]] + EPSV);
    }
    __syncthreads();

    // ---- main loop: producer waves gather chunk c+1, wave 0 recurses chunk c ----
    float a_even = NEGV, a_odd = NEGV;

    for (int c = 0; c < NCH; ++c) {
        const int cur = c & 1;
        if (tid >= 64) {
            if (c + 1 < NCH) {
                const int nxt = cur ^ 1;
                const int base_t = (c + 1) * CH;
                for (int idx = tid - 64; idx < CH * St; idx += 192) {
                    int tt = idx / St;
                    int s = idx - tt * St;
                    lp[nxt][tt][s] = __logf(yp[(base_t + tt) * Ct + ext_cls[s]] + EPSV);
                }
            }
        } else {
            // wave 0: alpha recursion over CH timesteps
            #pragma unroll 4
            for (int tt = 0; tt < CH; ++tt) {
                const bool act = (lane < 33);
                float le = NEGV, lo = NEGV;
                if (act) {
                    le = lp[cur][tt][2 * lane];
                    if (lane < 32) lo = lp[cur][tt][2 * lane + 1];
                }
                float pe = __shfl_up(a_even, 1);
                float po = __shfl_up(a_odd, 1);
                if (lane == 0) { pe = NEGV; po = NEGV; }
                (void)pe;
                if (act) {
                    int g = c * CH + tt;
                    if (g == 0) {
                        a_even = (lane == 0) ? le : NEGV;
                        a_odd  = (lane == 0) ? lo : NEGV;
                    } else {
                        // even state s=2i: blanks, no skip: a1=a[s], a2=a[s-1]
                        float ne = le + lae2(a_even, po);
                        // odd state s=2i+1: a1=a[s], a2=a[s-1]=a_even(old), a3=a[s-2]=po if allowed
                        float no = NEGV;
                        if (lane < 32) {
                            float a3 = skip_ok[2 * lane + 1] ? po : NEGV;
                            no = lo + lae3(a_odd, a_even, a3);
                        }
                        a_even = ne;
                        a_odd = no;
                    }
                }
            }
        }
        __syncthreads();
    }

    // ---- epilogue: spill alpha, compute loss ----
    if (tid < 64 && lane < 33) {
        alpha_f[2 * lane] = a_even;
        if (lane < 32) alpha_f[2 * lane + 1] = a_odd;
    }
    __syncthreads();
    if (tid == 0) {
        int ll = s_ll;
        int i1 = 2 * ll;
        int i2 = 2 * ll - 1;
        float v1 = alpha_f[i1];
        float v2 = (i2 >= 0) ? alpha_f[i2] : NEGV;
        out[b] = -lae2(v1, v2);
    }
}

extern "C" void kernel_launch(void* const* d_in, const int* in_sizes, int n_in,
                              void* d_out, int out_size, void* d_ws, size_t ws_size,
                              hipStream_t stream) {
    const int* y_true = (const int*)d_in[0];
    const float* y_pred = (const float*)d_in[1];
    float* out = (float*)d_out;
    (void)in_sizes; (void)n_in; (void)out_size; (void)d_ws; (void)ws_size;
    ctc_kernel<<<Bt, 256, 0, stream>>>(y_true, y_pred, out);
}